// Round 3
// baseline (235.361 us; speedup 1.0000x reference)
//
#include <hip/hip_runtime.h>
#include <hip/hip_fp16.h>

namespace {

constexpr int S = 512;       // plane height/width
constexpr int C = 64;        // channels per plane
constexpr int NBINS = 192;   // 3 planes x 8x8 tiles of 64x64 texels
constexpr int SCAT_IT = 8;   // samples per thread in count/scatter

typedef float f32x4 __attribute__((ext_vector_type(4)));
struct alignas(8)  H4 { __half2 a, b; };
struct alignas(16) H8 { __half2 h[4]; };

__device__ __forceinline__ void project(const float* __restrict__ coords, int sp,
                                        int& s, int& p, float& ix, float& iy)
{
    s = sp / 3;
    p = sp - 3 * s;
    float cx = coords[3 * s + 0];
    float cy = coords[3 * s + 1];
    float cz = coords[3 * s + 2];
    // plane 0: (x,y)  plane 1: (x,z)  plane 2: (z,y)
    float gx = (p == 2) ? cz : cx;
    float gy = (p == 1) ? cz : cy;
    ix = (gx + 1.0f) * 256.0f - 0.5f;   // ((gx+1)*512 - 1) * 0.5, exact
    iy = (gy + 1.0f) * 256.0f - 0.5f;
}

__device__ __forceinline__ int bin_of(int p, float ix, float iy)
{
    int x0 = (int)floorf(ix), y0 = (int)floorf(iy);
    int xc0 = min(max(x0, 0), S - 1), yc0 = min(max(y0, 0), S - 1);
    return p * 64 + (yc0 >> 6) * 8 + (xc0 >> 6);
}

// ---------------------------------------------------------------------------
// Transpose (3, C, S, S) f32  ->  (3, S, S, C) f16
// ---------------------------------------------------------------------------
__global__ __launch_bounds__(256) void tp_transpose(const float* __restrict__ tp,
                                                    __half* __restrict__ dst)
{
    int b  = blockIdx.x;
    int xt = b & 7;
    int y  = (b >> 3) & (S - 1);
    int p  = b >> 12;
    int t  = threadIdx.x;
    int cq = t & 15;             // channels 4cq..4cq+3
    int xl = t >> 4;             // x = 4*xl..4*xl+3
    int xb = xt * 64;

    const float* src = tp + (size_t)p * C * (S * S) + (size_t)y * S + xb + xl * 4;

    float4 f[4];
    #pragma unroll
    for (int j = 0; j < 4; ++j)
        f[j] = *reinterpret_cast<const float4*>(src + (size_t)(4 * cq + j) * (S * S));

    __half* ob = dst + ((size_t)(p * S + y) * S + xb) * C + 4 * cq;

    #pragma unroll
    for (int kx = 0; kx < 4; ++kx) {
        H4 h;
        h.a = __floats2half2_rn(((const float*)&f[0])[kx], ((const float*)&f[1])[kx]);
        h.b = __floats2half2_rn(((const float*)&f[2])[kx], ((const float*)&f[3])[kx]);
        *reinterpret_cast<H4*>(ob + (size_t)(xl * 4 + kx) * C) = h;
    }
}

// ---------------------------------------------------------------------------
// Binning pass 1: histogram of sample-planes over 192 (plane, tile) bins.
// ---------------------------------------------------------------------------
__global__ __launch_bounds__(256) void tp_count(const float* __restrict__ coords,
                                                int* __restrict__ hist, int total_sp)
{
    __shared__ int lh[NBINS];
    int t = threadIdx.x;
    if (t < NBINS) lh[t] = 0;
    __syncthreads();
    int base = blockIdx.x * (256 * SCAT_IT);
    #pragma unroll
    for (int it = 0; it < SCAT_IT; ++it) {
        int sp = base + it * 256 + t;
        if (sp < total_sp) {
            int s, p; float ix, iy;
            project(coords, sp, s, p, ix, iy);
            atomicAdd(&lh[bin_of(p, ix, iy)], 1);
        }
    }
    __syncthreads();
    if (t < NBINS && lh[t]) atomicAdd(&hist[t], lh[t]);
}

// ---------------------------------------------------------------------------
// Binning pass 2: exclusive prefix scan of 192 bins (single block).
// ---------------------------------------------------------------------------
__global__ __launch_bounds__(256) void tp_scan(const int* __restrict__ hist,
                                               int* __restrict__ cursor)
{
    __shared__ int v[256];
    int t = threadIdx.x;
    int mine = (t < NBINS) ? hist[t] : 0;
    v[t] = mine;
    __syncthreads();
    #pragma unroll
    for (int off = 1; off < 256; off <<= 1) {
        int x = (t >= off) ? v[t - off] : 0;
        __syncthreads();
        v[t] += x;
        __syncthreads();
    }
    if (t < NBINS) cursor[t] = v[t] - mine;   // exclusive prefix
}

// ---------------------------------------------------------------------------
// Binning pass 3: scatter sp indices into bin-sorted order[].
// Block-aggregated: LDS ranks, one global atomic per (block, bin).
// ---------------------------------------------------------------------------
__global__ __launch_bounds__(256) void tp_scatter(const float* __restrict__ coords,
                                                  int* __restrict__ cursor,
                                                  int* __restrict__ order, int total_sp)
{
    __shared__ int lh[NBINS];
    __shared__ int lbase[NBINS];
    int t = threadIdx.x;
    if (t < NBINS) lh[t] = 0;
    __syncthreads();
    int base = blockIdx.x * (256 * SCAT_IT);
    int bins[SCAT_IT], ranks[SCAT_IT];
    #pragma unroll
    for (int it = 0; it < SCAT_IT; ++it) {
        int sp = base + it * 256 + t;
        bins[it] = -1; ranks[it] = 0;
        if (sp < total_sp) {
            int s, p; float ix, iy;
            project(coords, sp, s, p, ix, iy);
            int bn = bin_of(p, ix, iy);
            bins[it] = bn;
            ranks[it] = atomicAdd(&lh[bn], 1);
        }
    }
    __syncthreads();
    if (t < NBINS && lh[t]) lbase[t] = atomicAdd(&cursor[t], lh[t]);
    __syncthreads();
    #pragma unroll
    for (int it = 0; it < SCAT_IT; ++it) {
        if (bins[it] >= 0)
            order[lbase[bins[it]] + ranks[it]] = base + it * 256 + t;
    }
}

// ---------------------------------------------------------------------------
// Binned sampler: 8 lanes per sample-plane, processed in bin-sorted order so
// each wave's gathers hit one L2-resident 512KB tile.  XCD swizzle keeps a
// bin's burst on one XCD's L2.  Lane t covers channels 8t..8t+7 (one dwordx4
// per corner).  Scattered-but-256B-contiguous nontemporal output stores.
// ---------------------------------------------------------------------------
__global__ __launch_bounds__(256) void tp_sample_binned(const float* __restrict__ coords,
                                                        const __half* __restrict__ planes,
                                                        const int* __restrict__ order,
                                                        float* __restrict__ out,
                                                        int total_sp, int nblocks, int do_swz)
{
    int b = blockIdx.x;
    if (do_swz) b = (b & 7) * (nblocks >> 3) + (b >> 3);
    int tid = b * 256 + threadIdx.x;
    int gi = tid >> 3;
    if (gi >= total_sp) return;
    int t = tid & 7;

    int sp = order[gi];
    int s, p; float ix, iy;
    project(coords, sp, s, p, ix, iy);

    float x0f = floorf(ix), y0f = floorf(iy);
    float wx = ix - x0f, wy = iy - y0f;
    int x0 = (int)x0f, y0 = (int)y0f;
    int x1 = x0 + 1,   y1 = y0 + 1;

    bool vx0 = ((unsigned)x0 < (unsigned)S);
    bool vx1 = ((unsigned)x1 < (unsigned)S);
    bool vy0 = ((unsigned)y0 < (unsigned)S);
    bool vy1 = ((unsigned)y1 < (unsigned)S);

    float w00 = (vx0 && vy0) ? (1.0f - wy) * (1.0f - wx) : 0.0f;
    float w01 = (vx1 && vy0) ? (1.0f - wy) * wx          : 0.0f;
    float w10 = (vx0 && vy1) ? wy * (1.0f - wx)          : 0.0f;
    float w11 = (vx1 && vy1) ? wy * wx                   : 0.0f;

    int xc0 = min(max(x0, 0), S - 1), xc1 = min(max(x1, 0), S - 1);
    int yc0 = min(max(y0, 0), S - 1), yc1 = min(max(y1, 0), S - 1);

    const __half* pb = planes + (size_t)p * (S * S * C) + 8 * t;
    H8 v00 = *reinterpret_cast<const H8*>(pb + (size_t)(yc0 * S + xc0) * C);
    H8 v01 = *reinterpret_cast<const H8*>(pb + (size_t)(yc0 * S + xc1) * C);
    H8 v10 = *reinterpret_cast<const H8*>(pb + (size_t)(yc1 * S + xc0) * C);
    H8 v11 = *reinterpret_cast<const H8*>(pb + (size_t)(yc1 * S + xc1) * C);

    f32x4 lo, hi;
    #pragma unroll
    for (int k = 0; k < 4; ++k) {
        float2 a = __half22float2(v00.h[k]);
        float2 b2 = __half22float2(v01.h[k]);
        float2 c2 = __half22float2(v10.h[k]);
        float2 d = __half22float2(v11.h[k]);
        float rx = w00 * a.x + w01 * b2.x + w10 * c2.x + w11 * d.x;
        float ry = w00 * a.y + w01 * b2.y + w10 * c2.y + w11 * d.y;
        if (k < 2) { lo[2 * k] = rx; lo[2 * k + 1] = ry; }
        else       { hi[2 * (k - 2)] = rx; hi[2 * (k - 2) + 1] = ry; }
    }

    float* ob = out + (size_t)sp * 64 + 8 * t;
    __builtin_nontemporal_store(lo, reinterpret_cast<f32x4*>(ob));
    __builtin_nontemporal_store(hi, reinterpret_cast<f32x4*>(ob + 4));
}

// ---------------------------------------------------------------------------
// Unbinned sampler (fallback, R2 version): 8 lanes per sample-plane.
// ---------------------------------------------------------------------------
__global__ __launch_bounds__(256) void tp_sample(const float* __restrict__ coords,
                                                 const __half* __restrict__ planes,
                                                 float* __restrict__ out,
                                                 int total_sp)
{
    int tid = blockIdx.x * 256 + threadIdx.x;
    int gi = tid >> 3;
    if (gi >= total_sp) return;
    int t = tid & 7;

    int s, p; float ix, iy;
    project(coords, gi, s, p, ix, iy);

    float x0f = floorf(ix), y0f = floorf(iy);
    float wx = ix - x0f, wy = iy - y0f;
    int x0 = (int)x0f, y0 = (int)y0f;
    int x1 = x0 + 1,   y1 = y0 + 1;

    bool vx0 = ((unsigned)x0 < (unsigned)S);
    bool vx1 = ((unsigned)x1 < (unsigned)S);
    bool vy0 = ((unsigned)y0 < (unsigned)S);
    bool vy1 = ((unsigned)y1 < (unsigned)S);

    float w00 = (vx0 && vy0) ? (1.0f - wy) * (1.0f - wx) : 0.0f;
    float w01 = (vx1 && vy0) ? (1.0f - wy) * wx          : 0.0f;
    float w10 = (vx0 && vy1) ? wy * (1.0f - wx)          : 0.0f;
    float w11 = (vx1 && vy1) ? wy * wx                   : 0.0f;

    int xc0 = min(max(x0, 0), S - 1), xc1 = min(max(x1, 0), S - 1);
    int yc0 = min(max(y0, 0), S - 1), yc1 = min(max(y1, 0), S - 1);

    const __half* pb = planes + (size_t)p * (S * S * C) + 8 * t;
    H8 v00 = *reinterpret_cast<const H8*>(pb + (size_t)(yc0 * S + xc0) * C);
    H8 v01 = *reinterpret_cast<const H8*>(pb + (size_t)(yc0 * S + xc1) * C);
    H8 v10 = *reinterpret_cast<const H8*>(pb + (size_t)(yc1 * S + xc0) * C);
    H8 v11 = *reinterpret_cast<const H8*>(pb + (size_t)(yc1 * S + xc1) * C);

    f32x4 lo, hi;
    #pragma unroll
    for (int k = 0; k < 4; ++k) {
        float2 a = __half22float2(v00.h[k]);
        float2 b2 = __half22float2(v01.h[k]);
        float2 c2 = __half22float2(v10.h[k]);
        float2 d = __half22float2(v11.h[k]);
        float rx = w00 * a.x + w01 * b2.x + w10 * c2.x + w11 * d.x;
        float ry = w00 * a.y + w01 * b2.y + w10 * c2.y + w11 * d.y;
        if (k < 2) { lo[2 * k] = rx; lo[2 * k + 1] = ry; }
        else       { hi[2 * (k - 2)] = rx; hi[2 * (k - 2) + 1] = ry; }
    }

    float* ob = out + (size_t)gi * 64 + 8 * t;
    __builtin_nontemporal_store(lo, reinterpret_cast<f32x4*>(ob));
    __builtin_nontemporal_store(hi, reinterpret_cast<f32x4*>(ob + 4));
}

// ---------------------------------------------------------------------------
// Last-resort fallback: direct gather from channel-major f32 planes.
// ---------------------------------------------------------------------------
__global__ __launch_bounds__(256) void tp_sample_direct(const float* __restrict__ coords,
                                                        const float* __restrict__ tp,
                                                        float* __restrict__ out,
                                                        int total_sp)
{
    int tid = blockIdx.x * 256 + threadIdx.x;
    int gi = tid >> 4;
    if (gi >= total_sp) return;
    int t = tid & 15;

    int s, p; float ix, iy;
    project(coords, gi, s, p, ix, iy);

    float x0f = floorf(ix), y0f = floorf(iy);
    float wx = ix - x0f, wy = iy - y0f;
    int x0 = (int)x0f, y0 = (int)y0f;
    int x1 = x0 + 1,   y1 = y0 + 1;

    bool vx0 = ((unsigned)x0 < (unsigned)S);
    bool vx1 = ((unsigned)x1 < (unsigned)S);
    bool vy0 = ((unsigned)y0 < (unsigned)S);
    bool vy1 = ((unsigned)y1 < (unsigned)S);

    float w00 = (vx0 && vy0) ? (1.0f - wy) * (1.0f - wx) : 0.0f;
    float w01 = (vx1 && vy0) ? (1.0f - wy) * wx          : 0.0f;
    float w10 = (vx0 && vy1) ? wy * (1.0f - wx)          : 0.0f;
    float w11 = (vx1 && vy1) ? wy * wx                   : 0.0f;

    int xc0 = min(max(x0, 0), S - 1), xc1 = min(max(x1, 0), S - 1);
    int yc0 = min(max(y0, 0), S - 1), yc1 = min(max(y1, 0), S - 1);

    int o00 = yc0 * S + xc0, o01 = yc0 * S + xc1;
    int o10 = yc1 * S + xc0, o11 = yc1 * S + xc1;

    const float* pb = tp + (size_t)p * C * (S * S);
    float r[4];
    #pragma unroll
    for (int j = 0; j < 4; ++j) {
        const float* ch = pb + (size_t)(4 * t + j) * (S * S);
        r[j] = w00 * ch[o00] + w01 * ch[o01] + w10 * ch[o10] + w11 * ch[o11];
    }
    float4 v = make_float4(r[0], r[1], r[2], r[3]);
    *reinterpret_cast<float4*>(out + (size_t)gi * 64 + 4 * t) = v;
}

__global__ void tp_zero_hist(int* __restrict__ hist)
{
    int t = threadIdx.x;
    if (t < NBINS) hist[t] = 0;
}

} // namespace

extern "C" void kernel_launch(void* const* d_in, const int* in_sizes, int n_in,
                              void* d_out, int out_size, void* d_ws, size_t ws_size,
                              hipStream_t stream)
{
    const float* coords  = (const float*)d_in[0];  // (N, M, 3) f32
    const float* tplanes = (const float*)d_in[1];  // (1, 3, C, S, S) f32
    float* out = (float*)d_out;                    // (N, M, 3*C) f32

    int total_sp = in_sizes[0];                    // N*M*3

    const size_t planesB    = (size_t)3 * S * S * C * sizeof(__half);  // 100.66 MB
    const size_t histOff    = planesB;
    const size_t cursorOff  = planesB + 1024;
    const size_t orderOff   = planesB + 4096;
    const size_t needBinned = orderOff + (size_t)total_sp * sizeof(int);

    if (ws_size >= needBinned) {
        __half* ws_planes = (__half*)d_ws;
        int* hist   = (int*)((char*)d_ws + histOff);
        int* cursor = (int*)((char*)d_ws + cursorOff);
        int* order  = (int*)((char*)d_ws + orderOff);

        int nb_cs = (total_sp + 256 * SCAT_IT - 1) / (256 * SCAT_IT);
        int nb_sm = (total_sp * 8 + 255) / 256;
        int do_swz = ((nb_sm & 7) == 0) ? 1 : 0;

        tp_zero_hist<<<1, 256, 0, stream>>>(hist);
        tp_count<<<nb_cs, 256, 0, stream>>>(coords, hist, total_sp);
        tp_scan<<<1, 256, 0, stream>>>(hist, cursor);
        tp_scatter<<<nb_cs, 256, 0, stream>>>(coords, cursor, order, total_sp);
        tp_transpose<<<3 * S * 8, 256, 0, stream>>>(tplanes, ws_planes);
        tp_sample_binned<<<nb_sm, 256, 0, stream>>>(coords, ws_planes, order, out,
                                                    total_sp, nb_sm, do_swz);
    } else if (ws_size >= planesB) {
        __half* ws_planes = (__half*)d_ws;
        tp_transpose<<<3 * S * 8, 256, 0, stream>>>(tplanes, ws_planes);
        int nb_sm = (total_sp * 8 + 255) / 256;
        tp_sample<<<nb_sm, 256, 0, stream>>>(coords, ws_planes, out, total_sp);
    } else {
        int nb_sm = (total_sp * 16 + 255) / 256;
        tp_sample_direct<<<nb_sm, 256, 0, stream>>>(coords, tplanes, out, total_sp);
    }
}